// Round 15
// baseline (184.829 us; speedup 1.0000x reference)
//
#include <hip/hip_runtime.h>
#include <cfloat>
#include <cstdint>

#define AN 100000   // anchors
#define GN 512      // ground truths
#define NC 80       // classes
#define KK 13       // topk

#define CHUNKS 8
#define CH_LEN 12800              // 25 full 512-tiles; last chunk 10400 = 20 tiles + 160
#define DUMP 16                   // dump slots per (g, chunk): 13 + pad
#define GSLICE 8
#define GPS (GN / GSLICE)         // 64

typedef unsigned long long ull;

// fast reciprocal: v_rcp_f32 (<=1 ulp); outputs bf16-compared (threshold 1.6)
__device__ __forceinline__ float rcpf(float x)
{
    float r; asm("v_rcp_f32 %0, %1" : "=v"(r) : "v"(x)); return r;
}

// 6th-root with downward margin. Margin 1e-4 >> ulp error of rcp/log/exp
// chains, so  metric > th  ==>  iou6 > th  ==>  inter > c*(uni+eps).
__device__ __forceinline__ float root6_down(float th)
{
    return exp2f(log2f(th) * (1.0f / 6.0f)) * 0.9999f;   // th=0 -> 0 (th>=0 post-flush)
}

// iou^6 (no score) — argmax/fallback paths
__device__ __forceinline__ float iou6r(float4 g, float ga, float4 p)
{
    float pa = (p.z - p.x) * (p.w - p.y);
    float ltx = fmaxf(g.x, p.x), lty = fmaxf(g.y, p.y);
    float rbx = fminf(g.z, p.z), rby = fminf(g.w, p.w);
    float w = fmaxf(rbx - ltx, 0.0f), h = fmaxf(rby - lty, 0.0f);
    float inter = w * h;
    float uni = ga + pa - inter;
    float iou = inter * rcpf(uni + 1e-9f);
    float i2 = iou * iou;
    return i2 * i2 * i2;
}

// order-preserving float->uint map (total order; works for -FLT_MAX sentinel)
__device__ __forceinline__ unsigned f2ord(float f)
{
    unsigned b = __float_as_uint(f);
    return b ^ (unsigned)(((int)b >> 31) | 0x80000000);
}
__device__ __forceinline__ float ord2f(unsigned u)
{
    unsigned b = (u & 0x80000000u) ? (u ^ 0x80000000u) : ~u;
    return __uint_as_float(b);
}

// compare-swap: keep better (value desc, index asc) in (va, ia)
__device__ __forceinline__ void csw(float& va, int& ia, float& vb, int& ib)
{
    bool sw = (va < vb) || (va == vb && ia > ib);
    float tv = sw ? vb : va; int ti = sw ? ib : ia;
    vb = sw ? va : vb; ib = sw ? ia : ib;
    va = tv; ia = ti;
}

// wave-synchronous LDS fence
__device__ __forceinline__ void wsync()
{
    __builtin_amdgcn_sched_barrier(0);
    asm volatile("s_waitcnt lgkmcnt(0)" ::: "memory");
    __builtin_amdgcn_sched_barrier(0);
}

// Exact top-13 of {incumbents (lane r<13 holds rank r) ∪ cand[0..n)} where
// candidates are (inter, uni+eps, idx) triples. Metric computed here with
// BIT-IDENTICAL op order (iou=in*rcp(ue); i6; m=sc*i6); scores gathered
// (8/lane max). n <= 512. Returns the 13th-best metric (new threshold).
__device__ float flush_f(int lane, int n,
                         const float* c_in, const float* c_ue, const int* c_ix,
                         const float* __restrict__ srow,
                         float& inc_v, int& inc_i)
{
    wsync();                               // appended cand visible wave-wide
    float v[8]; int ix[8];
    #pragma unroll
    for (int k = 0; k < 8; ++k) {
        int j = lane + (k << 6);
        bool ok = j < n;
        float in = ok ? c_in[j] : 0.0f;
        float ue = ok ? c_ue[j] : 1.0f;
        int   ai = ok ? c_ix[j] : 0;
        float iou = in * rcpf(ue);
        float i2 = iou * iou;
        float i6 = i2 * i2 * i2;
        float sc = srow[ai];               // gather (flush-only)
        v[k]  = ok ? sc * i6 : -FLT_MAX;
        ix[k] = ok ? ai : 0x7fffffff;
    }
    csw(v[0],ix[0],v[1],ix[1]); csw(v[2],ix[2],v[3],ix[3]);
    csw(v[4],ix[4],v[5],ix[5]); csw(v[6],ix[6],v[7],ix[7]);
    csw(v[0],ix[0],v[2],ix[2]); csw(v[1],ix[1],v[3],ix[3]);
    csw(v[4],ix[4],v[6],ix[6]); csw(v[5],ix[5],v[7],ix[7]);
    csw(v[1],ix[1],v[2],ix[2]); csw(v[5],ix[5],v[6],ix[6]);
    csw(v[0],ix[0],v[4],ix[4]); csw(v[1],ix[1],v[5],ix[5]);
    csw(v[2],ix[2],v[6],ix[6]); csw(v[3],ix[3],v[7],ix[7]);
    csw(v[2],ix[2],v[4],ix[4]); csw(v[3],ix[3],v[5],ix[5]);
    csw(v[1],ix[1],v[2],ix[2]); csw(v[3],ix[3],v[4],ix[4]);
    csw(v[5],ix[5],v[6],ix[6]);
    bool c[8];
    #pragma unroll
    for (int j = 0; j < 8; ++j)
        c[j] = (v[j] > inc_v) || (v[j] == inc_v && ix[j] < inc_i);
    float h[9]; int hi[9];
    h[0] = c[0] ? v[0] : inc_v;  hi[0] = c[0] ? ix[0] : inc_i;
    #pragma unroll
    for (int j = 1; j < 8; ++j) {
        h[j]  = c[j] ? v[j]  : (c[j-1] ? inc_v : v[j-1]);
        hi[j] = c[j] ? ix[j] : (c[j-1] ? inc_i : ix[j-1]);
    }
    h[8] = c[7] ? inc_v : v[7];  hi[8] = c[7] ? inc_i : ix[7];

    float th = -FLT_MAX;
    #pragma unroll
    for (int r = 0; r < KK; ++r) {
        ull myp = ((ull)f2ord(h[0]) << 32) | (unsigned)(~hi[0]);
        ull p = myp;
        #pragma unroll
        for (int o = 32; o >= 1; o >>= 1) {
            ull q = __shfl_xor(p, o);
            p = p > q ? p : q;
        }
        float wv = ord2f((unsigned)(p >> 32));
        int   wi = (int)~((unsigned)p);
        if (lane == r) { inc_v = wv; inc_i = wi; }
        bool pop = (myp == p);
        #pragma unroll
        for (int j = 0; j < 8; ++j) {
            h[j]  = pop ? h[j+1]  : h[j];
            hi[j] = pop ? hi[j+1] : hi[j];
        }
        h[8]  = pop ? -FLT_MAX   : h[8];
        hi[8] = pop ? 0x7fffffff : hi[8];
        th = wv;
    }
    return th;
}

// Insert into register-resident sorted-13 (fallback kernels only).
__device__ __forceinline__ void insert13(float* v, int* ix, float m, int a)
{
    bool worse = (m < v[KK - 1]) || (m == v[KK - 1] && a > ix[KK - 1]);
    if (worse) return;
    int p = 0;
    #pragma unroll
    for (int j = 0; j < KK; ++j)
        p += ((v[j] > m) || (v[j] == m && ix[j] < a)) ? 1 : 0;
    #pragma unroll
    for (int j = KK - 1; j >= 1; --j) {
        bool sh = (j > p);
        v[j]  = sh ? v[j - 1]  : v[j];
        ix[j] = sh ? ix[j - 1] : ix[j];
    }
    #pragma unroll
    for (int j = 0; j < KK; ++j) if (j == p) { v[j] = m; ix[j] = a; }
}

// ---------------- anchor areas (plain pa, eps NOT folded — keeps op order) ----------------
__global__ __launch_bounds__(256) void area_kernel(
    const float* __restrict__ pd_bboxes, float* __restrict__ paArr)
{
    int a = blockIdx.x * 256 + threadIdx.x;
    if (a >= AN) return;
    float4 p = ((const float4*)pd_bboxes)[a];
    paArr[a] = (p.z - p.x) * (p.w - p.y);
}

// ---------------- pd_scores [AN][NC] -> scT [NC][AN] ----------------
__global__ __launch_bounds__(256) void transpose_scores(
    const float* __restrict__ ps, float* __restrict__ scT)
{
    __shared__ float tile[64][NC + 1];
    int a0 = blockIdx.x * 64;
    int tid = threadIdx.x;
    for (int i = tid; i < 64 * NC / 4; i += 256) {
        int fi = i * 4;
        int a = fi / NC, c = fi % NC;
        if (a0 + a < AN) {
            float4 v = *reinterpret_cast<const float4*>(ps + (size_t)(a0 + a) * NC + c);
            tile[a][c] = v.x; tile[a][c + 1] = v.y; tile[a][c + 2] = v.z; tile[a][c + 3] = v.w;
        }
    }
    __syncthreads();
    int j = tid & 63, cg = tid >> 6;
    int a = a0 + j;
    if (a < AN) {
        for (int c = cg; c < NC; c += 4)
            scT[(size_t)c * AN + a] = tile[j][c];
    }
}

// ---------------- argmax pass A1 (predicated) ----------------
__global__ __launch_bounds__(256) void argmax_part(
    const float* __restrict__ pd_bboxes,
    const int*   __restrict__ gt_labels,
    const float* __restrict__ gt_bboxes,
    const float* __restrict__ scT,
    ull* __restrict__ part)
{
    __shared__ float4 gb[GPS];
    __shared__ float  ga[GPS];
    __shared__ int    glb[GPS];
    int slice = blockIdx.x & (GSLICE - 1);
    int ab = (blockIdx.x >> 3) * 512;
    int tid = threadIdx.x;
    int g0 = slice * GPS;
    if (tid < GPS) {
        float4 bb = ((const float4*)gt_bboxes)[g0 + tid];
        gb[tid] = bb;
        ga[tid] = (bb.z - bb.x) * (bb.w - bb.y);
        glb[tid] = gt_labels[g0 + tid];
    }
    __syncthreads();
    int aa = ab + tid, ab2 = ab + 256 + tid;
    bool okA = aa < AN, okB = ab2 < AN;
    int ca = okA ? aa : AN - 1, cb = okB ? ab2 : AN - 1;
    float4 pba = ((const float4*)pd_bboxes)[ca];
    float4 pbb = ((const float4*)pd_bboxes)[cb];
    float bestA = -1.0f, bestB = -1.0f;
    int bgA = 0, bgB = 0;
    for (int i = 0; i < GPS; ++i) {
        float4 gx = gb[i];
        float gax = ga[i];
        int lab = glb[i];
        const float* srow = scT + (size_t)lab * AN;
        float i6a = iou6r(gx, gax, pba);
        float i6b = iou6r(gx, gax, pbb);
        float sa = (i6a > bestA) ? srow[ca] : 0.0f;   // predicated gather
        float sb = (i6b > bestB) ? srow[cb] : 0.0f;
        float ma = sa * i6a;
        float mb = sb * i6b;
        if (ma > bestA) { bestA = ma; bgA = i; }      // strict > => first-occurrence
        if (mb > bestB) { bestB = mb; bgB = i; }
    }
    if (okA)
        part[(size_t)slice * AN + aa] =
            ((ull)__float_as_uint(bestA) << 32) | (ull)(0xFFFFFFFFu - (unsigned)(g0 + bgA));
    if (okB)
        part[(size_t)slice * AN + ab2] =
            ((ull)__float_as_uint(bestB) << 32) | (ull)(0xFFFFFFFFu - (unsigned)(g0 + bgB));
}

// ---------------- argmax pass A2 ----------------
__global__ __launch_bounds__(256) void argmax_combine(
    const ull* __restrict__ part,
    const int* __restrict__ gt_labels,
    const float* __restrict__ gt_bboxes,
    float* __restrict__ out)
{
    int a = blockIdx.x * 256 + threadIdx.x;
    if (a >= AN) return;
    ull p = part[a];
    #pragma unroll
    for (int s = 1; s < GSLICE; ++s) {
        ull q = part[(size_t)s * AN + a];
        p = p > q ? p : q;
    }
    unsigned g = 0xFFFFFFFFu - (unsigned)(p & 0xFFFFFFFFull);
    float best = __uint_as_float((unsigned)(p >> 32));
    out[a] = (best <= 0.0f) ? (float)NC : (float)gt_labels[g];
    ((float4*)(out + AN))[a] = ((const float4*)gt_bboxes)[g];
    out[(size_t)5 * AN + a] = best;
}

// ---------------- topk pass 1 ----------------
// 4 waves/block at lb(256,4) — VGPR cap 128, no spilling (NEVER lb(,8):
// its 32-VGPR cap caused ~500MB scratch traffic in rounds 9/11).
// 8 anchors/lane/tile (512-tile): 8 independent iou chains hide VALU dep
// latency; pa preloaded (bit-identical ue op order); division-free superset
// filter; thin (in,ue,idx) append; flush computes exact metric + gathers.
template<bool FULL>
__device__ __forceinline__ void procB8(
    int tb, int aend, int lane, uint64_t lt,
    const float4* __restrict__ pd4, const float* __restrict__ paArr,
    const float* __restrict__ srow,
    float4 b, float gax, float& th, float& cth, int& cnt,
    float* c_in, float* c_ue, int* c_ix,
    float& inc_v, int& inc_i)
{
    int a[8]; float4 P[8]; float pa[8], in[8], ue[8];
    bool h[8];
    #pragma unroll
    for (int k = 0; k < 8; ++k) {
        a[k] = tb + lane + (k << 6);
        int ck = FULL ? a[k] : min(a[k], AN - 1);
        P[k] = pd4[ck];
        pa[k] = paArr[ck];
    }
    #pragma unroll
    for (int k = 0; k < 8; ++k) {
        float lx = fmaxf(b.x, P[k].x), ly = fmaxf(b.y, P[k].y);
        float rx = fminf(b.z, P[k].z), ry = fminf(b.w, P[k].w);
        float w = fmaxf(rx - lx, 0.0f), hh = fmaxf(ry - ly, 0.0f);
        in[k] = w * hh;
        ue[k] = gax + pa[k] - in[k] + 1e-9f;   // ((gax+pa)-in)+eps : exact ref order
        h[k] = (in[k] > cth * ue[k]) && (FULL || a[k] < aend);
    }
    bool any = false;
    #pragma unroll
    for (int k = 0; k < 8; ++k) any |= h[k];
    if (__any(any)) {
        #pragma unroll
        for (int half = 0; half < 2; ++half) {
            #pragma unroll
            for (int k = half * 4; k < half * 4 + 4; ++k) {
                uint64_t B = __ballot(h[k]);
                if (h[k]) { int p = cnt + __popcll(B & lt);
                            c_in[p] = in[k]; c_ue[p] = ue[k]; c_ix[p] = a[k]; }
                cnt += __popcll(B);
            }
            if (cnt >= 256) {             // cap: 255 + 256 = 511 < 512
                th = flush_f(lane, cnt, c_in, c_ue, c_ix, srow, inc_v, inc_i);
                cth = root6_down(th);
                cnt = 0;
            }
        }
    }
}

__global__ __launch_bounds__(256, 4) void topk_pass1(
    const float* __restrict__ pd_bboxes,
    const float* __restrict__ paArr,
    const int*   __restrict__ gt_labels,
    const float* __restrict__ gt_bboxes,
    const float* __restrict__ scT,
    float* __restrict__ out_v, int* __restrict__ out_i)
{
    __shared__ float cinA[4][512];
    __shared__ float cueA[4][512];
    __shared__ int   cixA[4][512];
    int w = threadIdx.x >> 6, lane = threadIdx.x & 63;
    float* c_in = cinA[w]; float* c_ue = cueA[w]; int* c_ix = cixA[w];
    uint64_t lt = (1ull << lane) - 1ull;
    int gid = blockIdx.x * 4 + w;
    int g = gid & (GN - 1), c = gid >> 9;

    float4 b = ((const float4*)gt_bboxes)[g];
    float gax = (b.z - b.x) * (b.w - b.y);
    int lab = gt_labels[g];
    const float* srow = scT + (size_t)lab * AN;
    const float4* pd4 = (const float4*)pd_bboxes;

    int base = c * CH_LEN;
    int len = min(CH_LEN, AN - base);
    int aend = base + len;
    int nfull = len >> 9;                 // 25 (chunks 0-6) or 20 (chunk 7)
    int rem = len & 511;                  // 0 or 160

    float th = -FLT_MAX, cth = -FLT_MAX;  // tile 0 floods -> immediate exact flush
    int cnt = 0;
    float inc_v = -FLT_MAX; int inc_i = 0x7fffffff;   // lane r<13: rank r

    int tb = base;
    for (int i = 0; i < nfull; ++i, tb += 512)
        procB8<true>(tb, aend, lane, lt, pd4, paArr, srow,
                     b, gax, th, cth, cnt, c_in, c_ue, c_ix, inc_v, inc_i);
    if (rem)
        procB8<false>(tb, aend, lane, lt, pd4, paArr, srow,
                      b, gax, th, cth, cnt, c_in, c_ue, c_ix, inc_v, inc_i);

    if (cnt > 0)
        flush_f(lane, cnt, c_in, c_ue, c_ix, srow, inc_v, inc_i);

    if (lane < DUMP) {
        size_t o = ((size_t)g * CHUNKS + c) * DUMP + lane;
        out_v[o] = (lane < KK) ? inc_v : -FLT_MAX;
        out_i[o] = (lane < KK) ? inc_i : 0x7fffffff;
    }
}

// ---------------- topk pass 2: zero row + merge 8x16 dumps + scatter ----------------
__global__ __launch_bounds__(256) void topk_finalize(
    const float* __restrict__ in_v, const int* __restrict__ in_i,
    float* __restrict__ mask)
{
    int g = blockIdx.x, tid = threadIdx.x;
    float4* row4 = (float4*)(mask + (size_t)g * AN);
    float4 z = make_float4(0.f, 0.f, 0.f, 0.f);
    for (int j = tid; j < AN / 4; j += 256) row4[j] = z;
    __syncthreads();
    if (tid >= 64) return;
    int lane = tid;
    size_t rb = (size_t)g * (CHUNKS * DUMP);     // 128 entries
    float v0 = in_v[rb + lane], v1 = in_v[rb + 64 + lane];
    int   i0 = in_i[rb + lane], i1 = in_i[rb + 64 + lane];
    csw(v0, i0, v1, i1);
    #pragma unroll
    for (int r = 0; r < KK; ++r) {
        ull myp = ((ull)f2ord(v0) << 32) | (unsigned)(~i0);
        ull p = myp;
        #pragma unroll
        for (int o = 32; o >= 1; o >>= 1) {
            ull q = __shfl_xor(p, o);
            p = p > q ? p : q;
        }
        int wi = (int)~((unsigned)p);
        if (lane == r) mask[(size_t)g * AN + wi] = 1.0f;
        bool pop = (myp == p);
        v0 = pop ? v1 : v0;          i0 = pop ? i1 : i0;
        v1 = pop ? -FLT_MAX : v1;    i1 = pop ? 0x7fffffff : i1;
    }
}

// ---------------- fallbacks (small workspace) ----------------
__global__ __launch_bounds__(256) void argmax_kernel(
    const float* __restrict__ pd_scores,
    const float* __restrict__ pd_bboxes,
    const int*   __restrict__ gt_labels,
    const float* __restrict__ gt_bboxes,
    const float* __restrict__ scT, int use_t,
    float* __restrict__ out)
{
    __shared__ float4 gb[GN];
    __shared__ float  ga[GN];
    __shared__ int    gl[GN];
    int tid = threadIdx.x;
    for (int g = tid; g < GN; g += 256) {
        float4 b = reinterpret_cast<const float4*>(gt_bboxes)[g];
        gb[g] = b;
        ga[g] = (b.z - b.x) * (b.w - b.y);
        gl[g] = gt_labels[g];
    }
    __syncthreads();
    int a = blockIdx.x * 256 + tid;
    if (a >= AN) return;
    float4 pb = reinterpret_cast<const float4*>(pd_bboxes)[a];
    float best = -1.0f; int bg = 0;
    for (int g = 0; g < GN; ++g) {
        int lab = gl[g];
        float sc = use_t ? scT[(size_t)lab * AN + a] : pd_scores[(size_t)a * NC + lab];
        float m = sc * iou6r(gb[g], ga[g], pb);
        if (m > best) { best = m; bg = g; }
    }
    out[a] = (best <= 0.0f) ? (float)NC : (float)gl[bg];
    reinterpret_cast<float4*>(out + AN)[a] = gb[bg];
    out[5 * AN + a] = best;
}

__global__ __launch_bounds__(256) void topk_kernel_fallback(
    const float* __restrict__ pd_scores,
    const float* __restrict__ pd_bboxes,
    const int*   __restrict__ gt_labels,
    const float* __restrict__ gt_bboxes,
    const float* __restrict__ scT, int use_t,
    float* __restrict__ mask)
{
    __shared__ float sv[256 * KK];
    __shared__ int   si[256 * KK];
    int g = blockIdx.x, tid = threadIdx.x;
    float4 b = reinterpret_cast<const float4*>(gt_bboxes)[g];
    float gax = (b.z - b.x) * (b.w - b.y);
    int lab = gt_labels[g];
    float v[KK]; int idx[KK];
    #pragma unroll
    for (int j = 0; j < KK; ++j) { v[j] = -FLT_MAX; idx[j] = 0x7fffffff; }
    for (int a = tid; a < AN; a += 256) {
        float4 pb = reinterpret_cast<const float4*>(pd_bboxes)[a];
        float sc = use_t ? scT[(size_t)lab * AN + a] : pd_scores[(size_t)a * NC + lab];
        float m = sc * iou6r(b, gax, pb);
        insert13(v, idx, m, a);
    }
    #pragma unroll
    for (int j = 0; j < KK; ++j) { sv[tid * KK + j] = v[j]; si[tid * KK + j] = idx[j]; }
    for (int off = 128; off >= 1; off >>= 1) {
        __syncthreads();
        if (tid < off) {
            int i = 0, jj = 0;
            float ov[KK]; int oi[KK];
            #pragma unroll
            for (int t = 0; t < KK; ++t) {
                float va = sv[tid * KK + i];          int ia = si[tid * KK + i];
                float vb = sv[(tid + off) * KK + jj]; int ib = si[(tid + off) * KK + jj];
                bool ta = (va > vb) || (va == vb && ia < ib);
                ov[t] = ta ? va : vb; oi[t] = ta ? ia : ib;
                i += ta ? 1 : 0; jj += ta ? 0 : 1;
            }
            #pragma unroll
            for (int t = 0; t < KK; ++t) { sv[tid * KK + t] = ov[t]; si[tid * KK + t] = oi[t]; }
        }
    }
    __syncthreads();
    if (tid < KK) mask[(size_t)g * AN + si[tid]] = 1.0f;
}

extern "C" void kernel_launch(void* const* d_in, const int* in_sizes, int n_in,
                              void* d_out, int out_size, void* d_ws, size_t ws_size,
                              hipStream_t stream)
{
    const float* pd_scores = (const float*)d_in[0];
    const float* pd_bboxes = (const float*)d_in[1];
    const int*   gt_labels = (const int*)d_in[2];
    const float* gt_bboxes = (const float*)d_in[3];
    float* out  = (float*)d_out;
    float* mask = out + (size_t)6 * AN;

    const size_t scT_b  = (size_t)NC * AN * sizeof(float);           // 32.0 MB
    const size_t auxn   = (size_t)GN * CHUNKS * DUMP;                // 65536
    const size_t aux_b  = auxn * 8;                                  // 0.5 MB
    const size_t part_b = (size_t)GSLICE * AN * sizeof(ull);         // 6.4 MB
    const size_t pa_b   = (size_t)AN * sizeof(float);                // 0.4 MB

    float* scT   = (float*)d_ws;
    float* aux_v = (float*)((char*)d_ws + scT_b);
    int*   aux_i = (int*)(aux_v + auxn);
    ull*   part  = (ull*)((char*)d_ws + scT_b + aux_b);
    float* paArr = (float*)((char*)d_ws + scT_b + aux_b + part_b);

    if (ws_size >= scT_b + aux_b + part_b + pa_b) {
        area_kernel<<<(AN + 255) / 256, 256, 0, stream>>>(pd_bboxes, paArr);
        transpose_scores<<<(AN + 63) / 64, 256, 0, stream>>>(pd_scores, scT);
        topk_pass1<<<GN * CHUNKS / 4, 256, 0, stream>>>(
            pd_bboxes, paArr, gt_labels, gt_bboxes, scT, aux_v, aux_i);
        topk_finalize<<<GN, 256, 0, stream>>>(aux_v, aux_i, mask);
        argmax_part<<<((AN + 511) / 512) * GSLICE, 256, 0, stream>>>(
            pd_bboxes, gt_labels, gt_bboxes, scT, part);
        argmax_combine<<<(AN + 255) / 256, 256, 0, stream>>>(
            part, gt_labels, gt_bboxes, out);
    } else if (ws_size >= scT_b) {
        hipMemsetAsync(mask, 0, (size_t)GN * AN * sizeof(float), stream);
        transpose_scores<<<(AN + 63) / 64, 256, 0, stream>>>(pd_scores, scT);
        argmax_kernel<<<(AN + 255) / 256, 256, 0, stream>>>(
            pd_scores, pd_bboxes, gt_labels, gt_bboxes, scT, 1, out);
        topk_kernel_fallback<<<GN, 256, 0, stream>>>(
            pd_scores, pd_bboxes, gt_labels, gt_bboxes, scT, 1, mask);
    } else {
        hipMemsetAsync(mask, 0, (size_t)GN * AN * sizeof(float), stream);
        argmax_kernel<<<(AN + 255) / 256, 256, 0, stream>>>(
            pd_scores, pd_bboxes, gt_labels, gt_bboxes, scT, 0, out);
        topk_kernel_fallback<<<GN, 256, 0, stream>>>(
            pd_scores, pd_bboxes, gt_labels, gt_bboxes, scT, 0, mask);
    }
}